// Round 1
// baseline (368.041 us; speedup 1.0000x reference)
//
#include <hip/hip_runtime.h>
#include <stdint.h>

// ---------------------------------------------------------------------------
// MultiHeadAttention fwd: B=4 S=2048 D=1024 H=16 DH=64, fp32 in/out.
// Pipeline: cast->bf16 | QKV GEMM (MFMA, bias, q*=0.125) | V transpose |
//           flash attention (causal, online softmax) | out GEMM (bias, fp32).
// ---------------------------------------------------------------------------

typedef __bf16 bf16;
typedef __attribute__((ext_vector_type(4))) __bf16 bf16x4;
typedef __attribute__((ext_vector_type(8))) __bf16 bf16x8;
typedef __attribute__((ext_vector_type(4))) float f32x4;

#define MFMA16(a, b, c) __builtin_amdgcn_mfma_f32_16x16x32_bf16((a), (b), (c), 0, 0, 0)

// async global->LDS, 16B per lane. LDS dest must be wave-uniform base;
// HW writes base + lane*16. Global src is per-lane.
#define GLOAD_LDS16(gp, lp)                                                    \
  __builtin_amdgcn_global_load_lds(                                            \
      (__attribute__((address_space(1))) void*)(gp),                           \
      (__attribute__((address_space(3))) void*)(lp), 16, 0, 0)

#define SB   2048              // sequence length
#define D3   3072              // 3*D
#define DD   1024              // D

// ---------------------------------------------------------------------------
// fp32 -> bf16 cast, 4 elements/thread/iter
// ---------------------------------------------------------------------------
__global__ __launch_bounds__(256) void cast_bf16_kernel(
    const float* __restrict__ in, bf16* __restrict__ out, int n4) {
  int stride = gridDim.x * blockDim.x;
  for (int i = blockIdx.x * blockDim.x + threadIdx.x; i < n4; i += stride) {
    float4 v = ((const float4*)in)[i];
    bf16x4 p;
    p[0] = (bf16)v.x; p[1] = (bf16)v.y; p[2] = (bf16)v.z; p[3] = (bf16)v.w;
    *(bf16x4*)(out + (size_t)i * 4) = p;
  }
}

// ---------------------------------------------------------------------------
// NT GEMM: C[m,n] = sum_k A[m,k]*Bw[n,k] + bias[n]
// OUTMODE 1: bf16 out, q-part (n<1024) scaled by 0.125. OUTMODE 0: fp32 out.
// 128x128 tile, BK=32, 256 thr (4 waves 2x2, each 64x64).
// ---------------------------------------------------------------------------
template <int OUTMODE>
__global__ __launch_bounds__(256) void gemm_bt_kernel(
    const bf16* __restrict__ A, const bf16* __restrict__ Bw,
    const float* __restrict__ bias, void* __restrict__ Cout,
    int M, int N, int K) {
  __shared__ __attribute__((aligned(16))) bf16 At[128 * 32];
  __shared__ __attribute__((aligned(16))) bf16 Bt[128 * 32];
  const int tid = threadIdx.x;
  const int w = tid >> 6, l = tid & 63;
  const int c = l & 15, g = l >> 4;
  const int wm = w >> 1, wn = w & 1;
  const int m0 = blockIdx.y * 128, n0 = blockIdx.x * 128;

  // staging: wave w covers rows [w*32, w*32+32); lane covers row l>>2, col (l&3)*8
  const int srow = w * 32 + (l >> 2);
  const int scol = (l & 3) * 8;
  const bf16* Ag = A + (size_t)(m0 + srow) * K + scol;
  const bf16* Bg = Bw + (size_t)(n0 + srow) * K + scol;
  char* AtB = (char*)At + w * 2048;
  char* BtB = (char*)Bt + w * 2048;

  f32x4 acc[4][4] = {};

  for (int k0 = 0; k0 < K; k0 += 32) {
    GLOAD_LDS16(Ag + k0,            AtB);
    GLOAD_LDS16(Ag + 16 * K + k0,   AtB + 1024);
    GLOAD_LDS16(Bg + k0,            BtB);
    GLOAD_LDS16(Bg + 16 * K + k0,   BtB + 1024);
    __syncthreads();   // drains vmcnt -> staged data visible

    bf16x8 aF[4], bF[4];
    const char* Ard = (const char*)At + (wm * 64 + c) * 64 + g * 16;
    const char* Brd = (const char*)Bt + (wn * 64 + c) * 64 + g * 16;
#pragma unroll
    for (int mi = 0; mi < 4; ++mi) aF[mi] = *(const bf16x8*)(Ard + mi * 1024);
#pragma unroll
    for (int ni = 0; ni < 4; ++ni) bF[ni] = *(const bf16x8*)(Brd + ni * 1024);
#pragma unroll
    for (int mi = 0; mi < 4; ++mi)
#pragma unroll
      for (int ni = 0; ni < 4; ++ni)
        acc[mi][ni] = MFMA16(aF[mi], bF[ni], acc[mi][ni]);
    __syncthreads();   // protect LDS before next stage
  }

  // epilogue: C/D layout col=lane&15, row=4*(lane>>4)+r  [measured m89/m91]
#pragma unroll
  for (int ni = 0; ni < 4; ++ni) {
    const int col = n0 + wn * 64 + ni * 16 + c;
    const float bv = bias[col];
#pragma unroll
    for (int mi = 0; mi < 4; ++mi) {
      const int row = m0 + wm * 64 + mi * 16 + 4 * g;
#pragma unroll
      for (int r = 0; r < 4; ++r) {
        float v = acc[mi][ni][r] + bv;
        if (OUTMODE == 1) {
          if (col < DD) v *= 0.125f;  // fold 1/sqrt(dh) into q
          ((bf16*)Cout)[(size_t)(row + r) * N + col] = (bf16)v;
        } else {
          ((float*)Cout)[(size_t)(row + r) * N + col] = v;
        }
      }
    }
  }
}

// ---------------------------------------------------------------------------
// V transpose: qkv v-part [b,s,h*64+d] -> vT[(bh*64+d)*2048 + s]
// 64x64 tiles through padded LDS (stride 72 keeps 16B-aligned rows).
// ---------------------------------------------------------------------------
__global__ __launch_bounds__(256) void vtrans_kernel(
    const bf16* __restrict__ qkv, bf16* __restrict__ vT) {
  __shared__ __attribute__((aligned(16))) bf16 tt[64 * 72];
  const int tid = threadIdx.x;
  const int bh = blockIdx.x >> 5, st = blockIdx.x & 31;
  const int b = bh >> 4, h = bh & 15;
  const int s0 = st * 64;
  const int sr = tid >> 3, c0 = (tid & 7) * 8;
#pragma unroll
  for (int i = 0; i < 2; ++i) {
    const int srr = sr + i * 32;
    bf16x8 v = *(const bf16x8*)(qkv + (size_t)(b * SB + s0 + srr) * D3 + 2 * DD + h * 64 + c0);
    *(bf16x8*)(&tt[srr * 72 + c0]) = v;
  }
  __syncthreads();
  const int d = tid >> 2;
#pragma unroll
  for (int i = 0; i < 2; ++i) {
    const int sc = (tid & 3) * 2 + i;
    bf16x8 v;
#pragma unroll
    for (int j = 0; j < 8; ++j) v[j] = tt[(sc * 8 + j) * 72 + d];
    *(bf16x8*)(vT + (size_t)(bh * 64 + d) * SB + s0 + sc * 8) = v;
  }
}

// ---------------------------------------------------------------------------
// Causal flash attention. Grid 1024: qt = bid&15 (q-tile of 128), bh = bid>>4.
// 4 waves x 32 q-rows. KV tiles of 128. K,V^T staged by global_load_lds with
// pre-swizzled source (LDS byte ^= (row&7)<<4 within row); P per-wave in LDS
// with the same XOR swizzle on both write and read sides.
// ---------------------------------------------------------------------------
__global__ __launch_bounds__(256) void attn_kernel(
    const bf16* __restrict__ qkv, const bf16* __restrict__ vT,
    bf16* __restrict__ o) {
  __shared__ __attribute__((aligned(16))) bf16 Kt[128 * 64];     // [kcol][d]  16KB
  __shared__ __attribute__((aligned(16))) bf16 Vt[64 * 128];     // [d][key]   16KB
  __shared__ __attribute__((aligned(16))) bf16 Pt[4][32 * 128];  // per-wave   32KB
  const int tid = threadIdx.x;
  const int w = tid >> 6, l = tid & 63;
  const int c = l & 15, g = l >> 4;
  const int qt = blockIdx.x & 15, bh = blockIdx.x >> 4;
  const int b = bh >> 4, h = bh & 15;
  const int pmaskr = (c & 7) << 4;  // read-side XOR (row&7)<<4 with row%8==c%8

  // Q fragments in registers (q already scaled by 0.125 at QKV store)
  const bf16* qg = qkv + (size_t)(b * SB) * D3 + h * 64;
  const int q0 = qt * 128 + w * 32;
  bf16x8 qf[2][2];
#pragma unroll
  for (int mi = 0; mi < 2; ++mi)
#pragma unroll
    for (int dk = 0; dk < 2; ++dk)
      qf[mi][dk] = *(const bf16x8*)(qg + (size_t)(q0 + mi * 16 + c) * D3 + dk * 32 + g * 8);

  f32x4 of[2][4] = {};
  float mreg[2][4], lreg[2][4];
#pragma unroll
  for (int mi = 0; mi < 2; ++mi)
#pragma unroll
    for (int r = 0; r < 4; ++r) { mreg[mi][r] = -1e30f; lreg[mi][r] = 0.f; }

  char* Pw = (char*)&Pt[w][0];
  const f32x4 zero = {0.f, 0.f, 0.f, 0.f};

  for (int kt = 0; kt <= qt; ++kt) {
    // ---- stage K tile [128][64], source col pre-swizzled
#pragma unroll
    for (int j = 0; j < 4; ++j) {
      const int row = w * 32 + j * 8 + (l >> 3);
      const int cs = ((l & 7) ^ (row & 7)) << 3;
      GLOAD_LDS16(qkv + (size_t)(b * SB + kt * 128 + row) * D3 + DD + h * 64 + cs,
                  (char*)Kt + w * 4096 + j * 1024);
    }
    // ---- stage V^T tile [64][128]
#pragma unroll
    for (int j = 0; j < 4; ++j) {
      const int row = w * 16 + j * 4 + (l >> 4);
      const int cs = ((l & 15) ^ (row & 7)) << 3;
      GLOAD_LDS16(vT + (size_t)(bh * 64 + row) * SB + kt * 128 + cs,
                  (char*)Vt + w * 4096 + j * 1024);
    }
    __syncthreads();

    // ---- QK^T: scores[q][kcol], 2 row-frags x 8 col-frags
    f32x4 sf[2][8];
#pragma unroll
    for (int f = 0; f < 8; ++f) {
      const char* kr = (const char*)Kt + (f * 16 + c) * 128;
      bf16x8 kb0 = *(const bf16x8*)(kr + ((g * 16) ^ pmaskr));
      bf16x8 kb1 = *(const bf16x8*)(kr + ((64 + g * 16) ^ pmaskr));
#pragma unroll
      for (int mi = 0; mi < 2; ++mi) {
        f32x4 t = MFMA16(qf[mi][0], kb0, zero);
        sf[mi][f] = MFMA16(qf[mi][1], kb1, t);
      }
    }

    if (kt == qt) {  // diagonal tile: causal mask
#pragma unroll
      for (int mi = 0; mi < 2; ++mi)
#pragma unroll
        for (int f = 0; f < 8; ++f)
#pragma unroll
          for (int r = 0; r < 4; ++r) {
            const int kc = f * 16 + c;
            const int qr = w * 32 + mi * 16 + 4 * g + r;
            if (kc > qr) sf[mi][f][r] = -1e30f;
          }
    }

    // ---- online softmax (wave-parallel; rows live in 16-lane subgroups)
#pragma unroll
    for (int mi = 0; mi < 2; ++mi) {
      float rmax[4];
#pragma unroll
      for (int r = 0; r < 4; ++r) {
        float mx = sf[mi][0][r];
#pragma unroll
        for (int f = 1; f < 8; ++f) mx = fmaxf(mx, sf[mi][f][r]);
        rmax[r] = mx;
      }
#pragma unroll
      for (int mk = 1; mk <= 8; mk <<= 1)
#pragma unroll
        for (int r = 0; r < 4; ++r)
          rmax[r] = fmaxf(rmax[r], __shfl_xor(rmax[r], mk, 64));

      float rsum[4];
#pragma unroll
      for (int r = 0; r < 4; ++r) {
        const float mnew = fmaxf(mreg[mi][r], rmax[r]);
        const float sc = __expf(mreg[mi][r] - mnew);
        mreg[mi][r] = mnew;
        lreg[mi][r] *= sc;
        rsum[r] = 0.f;
#pragma unroll
        for (int di = 0; di < 4; ++di) of[mi][di] [r] *= sc;
      }
#pragma unroll
      for (int f = 0; f < 8; ++f)
#pragma unroll
        for (int r = 0; r < 4; ++r) {
          const float p = __expf(sf[mi][f][r] - mreg[mi][r]);
          rsum[r] += p;
          const int qrow = mi * 16 + 4 * g + r;
          *(bf16*)(Pw + qrow * 256 + ((f * 32 + c * 2) ^ ((qrow & 7) << 4))) = (bf16)p;
        }
#pragma unroll
      for (int mk = 1; mk <= 8; mk <<= 1)
#pragma unroll
        for (int r = 0; r < 4; ++r) rsum[r] += __shfl_xor(rsum[r], mk, 64);
#pragma unroll
      for (int r = 0; r < 4; ++r) lreg[mi][r] += rsum[r];
    }

    asm volatile("s_waitcnt lgkmcnt(0)" ::: "memory");  // P writes -> reads (wave-local)
    __builtin_amdgcn_sched_barrier(0);

    // ---- PV: O[q][d] += P[q][k] * V[k][d]
#pragma unroll
    for (int kw = 0; kw < 4; ++kw) {
      bf16x8 pa[2];
#pragma unroll
      for (int mi = 0; mi < 2; ++mi)
        pa[mi] = *(const bf16x8*)(Pw + (mi * 16 + c) * 256 + ((kw * 64 + g * 16) ^ pmaskr));
#pragma unroll
      for (int di = 0; di < 4; ++di) {
        bf16x8 vb = *(const bf16x8*)((const char*)Vt + (di * 16 + c) * 256 +
                                     ((kw * 64 + g * 16) ^ pmaskr));
#pragma unroll
        for (int mi = 0; mi < 2; ++mi) of[mi][di] = MFMA16(pa[mi], vb, of[mi][di]);
      }
    }
    __syncthreads();  // all waves done with Kt/Vt before next stage
  }

  // ---- normalize + store
#pragma unroll
  for (int mi = 0; mi < 2; ++mi)
#pragma unroll
    for (int r = 0; r < 4; ++r) {
      const float inv = 1.0f / lreg[mi][r];
      const size_t row = (size_t)(b * SB + qt * 128 + w * 32 + mi * 16 + 4 * g + r);
#pragma unroll
      for (int di = 0; di < 4; ++di)
        o[row * DD + h * 64 + di * 16 + c] = (bf16)(of[mi][di][r] * inv);
    }
}

// ---------------------------------------------------------------------------
extern "C" void kernel_launch(void* const* d_in, const int* in_sizes, int n_in,
                              void* d_out, int out_size, void* d_ws, size_t ws_size,
                              hipStream_t stream) {
  const float* x  = (const float*)d_in[0];
  const float* w1 = (const float*)d_in[1];
  const float* b1 = (const float*)d_in[2];
  const float* w2 = (const float*)d_in[3];
  const float* b2 = (const float*)d_in[4];
  float* out = (float*)d_out;

  // ws carve-up (bf16): xb 16MB | w1b 6MB | w2b 2MB | qkv 48MB | vT 16MB | ob 16MB
  bf16* xb   = (bf16*)d_ws;
  bf16* w1b  = xb   + (size_t)8  * 1024 * 1024;
  bf16* w2b  = w1b  + (size_t)3  * 1024 * 1024;
  bf16* qkvb = w2b  + (size_t)1  * 1024 * 1024;
  bf16* vT   = qkvb + (size_t)8192 * 3072;
  bf16* ob   = vT   + (size_t)8  * 1024 * 1024;

  cast_bf16_kernel<<<2048, 256, 0, stream>>>(x,  xb,  (8 * 1024 * 1024) / 4);
  cast_bf16_kernel<<<768,  256, 0, stream>>>(w1, w1b, (3 * 1024 * 1024) / 4);
  cast_bf16_kernel<<<256,  256, 0, stream>>>(w2, w2b, (1 * 1024 * 1024) / 4);

  gemm_bt_kernel<1><<<dim3(24, 64), 256, 0, stream>>>(xb, w1b, b1, qkvb, 8192, 3072, 1024);
  vtrans_kernel<<<2048, 256, 0, stream>>>(qkvb, vT);
  attn_kernel<<<1024, 256, 0, stream>>>(qkvb, vT, ob);
  gemm_bt_kernel<0><<<dim3(8, 64), 256, 0, stream>>>(ob, w2b, b2, out, 8192, 1024, 1024);
}

// Round 2
// 197.217 us; speedup vs baseline: 1.8662x; 1.8662x over previous
//
#include <hip/hip_runtime.h>
#include <stdint.h>

// ---------------------------------------------------------------------------
// MultiHeadAttention fwd: B=4 S=2048 D=1024 H=16 DH=64, fp32 in/out.
// Pipeline: cast->bf16 | QKV GEMM (MFMA, bias, q*=0.125*log2e) | V transpose |
//           flash attention (causal, paired q-tiles, in-register softmax) |
//           out GEMM (bias, fp32).
// ---------------------------------------------------------------------------

typedef __bf16 bf16;
typedef __attribute__((ext_vector_type(4))) __bf16 bf16x4;
typedef __attribute__((ext_vector_type(8))) __bf16 bf16x8;
typedef __attribute__((ext_vector_type(4))) float f32x4;

#define MFMA16(a, b, c) __builtin_amdgcn_mfma_f32_16x16x32_bf16((a), (b), (c), 0, 0, 0)

#if __has_builtin(__builtin_amdgcn_exp2f)
#define EXP2F(x) __builtin_amdgcn_exp2f(x)
#else
#define EXP2F(x) exp2f(x)
#endif

// async global->LDS, 16B per lane. LDS dest is wave-uniform base + lane*16.
#define GLOAD_LDS16(gp, lp)                                                    \
  __builtin_amdgcn_global_load_lds(                                            \
      (__attribute__((address_space(1))) void*)(gp),                           \
      (__attribute__((address_space(3))) void*)(lp), 16, 0, 0)

#define SB   2048              // sequence length
#define D3   3072              // 3*D
#define DD   1024              // D
#define QSCALE 0.18033688011112042f   // 1/sqrt(64) * log2(e): exp -> exp2

// ---------------------------------------------------------------------------
// fp32 -> bf16 cast, 4 elements/thread/iter
// ---------------------------------------------------------------------------
__global__ __launch_bounds__(256) void cast_bf16_kernel(
    const float* __restrict__ in, bf16* __restrict__ out, int n4) {
  int stride = gridDim.x * blockDim.x;
  for (int i = blockIdx.x * blockDim.x + threadIdx.x; i < n4; i += stride) {
    float4 v = ((const float4*)in)[i];
    bf16x4 p;
    p[0] = (bf16)v.x; p[1] = (bf16)v.y; p[2] = (bf16)v.z; p[3] = (bf16)v.w;
    *(bf16x4*)(out + (size_t)i * 4) = p;
  }
}

// ---------------------------------------------------------------------------
// NT GEMM: C[m,n] = sum_k A[m,k]*Bw[n,k] + bias[n]
// OUTMODE 1: bf16 out, q-part (n<1024) scaled by QSCALE. OUTMODE 0: fp32 out.
// 128x128 tile, BK=32, 256 thr (4 waves 2x2, each 64x64).
// ---------------------------------------------------------------------------
template <int OUTMODE>
__global__ __launch_bounds__(256) void gemm_bt_kernel(
    const bf16* __restrict__ A, const bf16* __restrict__ Bw,
    const float* __restrict__ bias, void* __restrict__ Cout,
    int M, int N, int K) {
  __shared__ __attribute__((aligned(16))) bf16 At[128 * 32];
  __shared__ __attribute__((aligned(16))) bf16 Bt[128 * 32];
  const int tid = threadIdx.x;
  const int w = tid >> 6, l = tid & 63;
  const int c = l & 15, g = l >> 4;
  const int wm = w >> 1, wn = w & 1;
  const int m0 = blockIdx.y * 128, n0 = blockIdx.x * 128;

  const int srow = w * 32 + (l >> 2);
  const int scol = (l & 3) * 8;
  const bf16* Ag = A + (size_t)(m0 + srow) * K + scol;
  const bf16* Bg = Bw + (size_t)(n0 + srow) * K + scol;
  char* AtB = (char*)At + w * 2048;
  char* BtB = (char*)Bt + w * 2048;

  f32x4 acc[4][4] = {};

  for (int k0 = 0; k0 < K; k0 += 32) {
    GLOAD_LDS16(Ag + k0,            AtB);
    GLOAD_LDS16(Ag + 16 * K + k0,   AtB + 1024);
    GLOAD_LDS16(Bg + k0,            BtB);
    GLOAD_LDS16(Bg + 16 * K + k0,   BtB + 1024);
    __syncthreads();

    bf16x8 aF[4], bF[4];
    const char* Ard = (const char*)At + (wm * 64 + c) * 64 + g * 16;
    const char* Brd = (const char*)Bt + (wn * 64 + c) * 64 + g * 16;
#pragma unroll
    for (int mi = 0; mi < 4; ++mi) aF[mi] = *(const bf16x8*)(Ard + mi * 1024);
#pragma unroll
    for (int ni = 0; ni < 4; ++ni) bF[ni] = *(const bf16x8*)(Brd + ni * 1024);
#pragma unroll
    for (int mi = 0; mi < 4; ++mi)
#pragma unroll
      for (int ni = 0; ni < 4; ++ni)
        acc[mi][ni] = MFMA16(aF[mi], bF[ni], acc[mi][ni]);
    __syncthreads();
  }

#pragma unroll
  for (int ni = 0; ni < 4; ++ni) {
    const int col = n0 + wn * 64 + ni * 16 + c;
    const float bv = bias[col];
#pragma unroll
    for (int mi = 0; mi < 4; ++mi) {
      const int row = m0 + wm * 64 + mi * 16 + 4 * g;
#pragma unroll
      for (int r = 0; r < 4; ++r) {
        float v = acc[mi][ni][r] + bv;
        if (OUTMODE == 1) {
          if (col < DD) v *= QSCALE;  // fold 1/sqrt(dh)*log2e into q
          ((bf16*)Cout)[(size_t)(row + r) * N + col] = (bf16)v;
        } else {
          ((float*)Cout)[(size_t)(row + r) * N + col] = v;
        }
      }
    }
  }
}

// ---------------------------------------------------------------------------
// V transpose: qkv v-part [b,s,h*64+d] -> vT[(bh*64+d)*2048 + s]
// ---------------------------------------------------------------------------
__global__ __launch_bounds__(256) void vtrans_kernel(
    const bf16* __restrict__ qkv, bf16* __restrict__ vT) {
  __shared__ __attribute__((aligned(16))) bf16 tt[64 * 72];
  const int tid = threadIdx.x;
  const int bh = blockIdx.x >> 5, st = blockIdx.x & 31;
  const int b = bh >> 4, h = bh & 15;
  const int s0 = st * 64;
  const int sr = tid >> 3, c0 = (tid & 7) * 8;
#pragma unroll
  for (int i = 0; i < 2; ++i) {
    const int srr = sr + i * 32;
    bf16x8 v = *(const bf16x8*)(qkv + (size_t)(b * SB + s0 + srr) * D3 + 2 * DD + h * 64 + c0);
    *(bf16x8*)(&tt[srr * 72 + c0]) = v;
  }
  __syncthreads();
  const int d = tid >> 2;
#pragma unroll
  for (int i = 0; i < 2; ++i) {
    const int sc = (tid & 3) * 2 + i;
    bf16x8 v;
#pragma unroll
    for (int j = 0; j < 8; ++j) v[j] = tt[(sc * 8 + j) * 72 + d];
    *(bf16x8*)(vT + (size_t)(bh * 64 + d) * SB + s0 + sc * 8) = v;
  }
}

// ---------------------------------------------------------------------------
// Causal flash attention, paired q-tiles for load balance.
// Grid 512: pair = bid&7, bh = bid>>3. qtA = pair (light), qtB = 15-pair (heavy).
// 4 waves x 32 q-rows per tile. KV tiles of 128 staged once, used by both.
// Swapped MFMA structure:
//   S^T = mfma(K, Q): lane holds P[q = mi*16+c][k = f*16+4g+r]  (in regs)
//   softmax: lane-local 32-max/sum + shfl_xor(16,32) across g
//   O^T = mfma(V^T-frag, P-frag): of[mi][di][r] = O[q = mi*16+c][d = di*16+4g+r]
// P never touches LDS; stats and O live on the same lanes (rescale lane-local).
// ---------------------------------------------------------------------------
__global__ __launch_bounds__(256, 2) void attn_kernel(
    const bf16* __restrict__ qkv, const bf16* __restrict__ vT,
    bf16* __restrict__ o) {
  __shared__ __attribute__((aligned(16))) bf16 Kt[128 * 64];     // [kcol][d] 16KB
  __shared__ __attribute__((aligned(16))) bf16 Vt[64 * 128];     // [d][key]  16KB
  const int tid = threadIdx.x;
  const int w = tid >> 6, l = tid & 63;
  const int c = l & 15, g = l >> 4;
  const int pair = blockIdx.x & 7, bh = blockIdx.x >> 3;
  const int b = bh >> 4, h = bh & 15;
  const int qtA = pair, qtB = 15 - pair;
  const int swz = (c & 7) << 4;   // read-side XOR; staged rows pre-swizzled by (row&7)

  const bf16* qg = qkv + (size_t)(b * SB) * D3 + h * 64;

  // Q fragments for both tiles (B-operand layout: lane(c,g) = Q[q][d=dk*32+g*8..+7])
  bf16x8 qfA[2][2], qfB[2][2];
#pragma unroll
  for (int mi = 0; mi < 2; ++mi)
#pragma unroll
    for (int dk = 0; dk < 2; ++dk) {
      qfA[mi][dk] = *(const bf16x8*)(qg + (size_t)(qtA * 128 + w * 32 + mi * 16 + c) * D3 + dk * 32 + g * 8);
      qfB[mi][dk] = *(const bf16x8*)(qg + (size_t)(qtB * 128 + w * 32 + mi * 16 + c) * D3 + dk * 32 + g * 8);
    }

  f32x4 ofA[2][4] = {}, ofB[2][4] = {};
  float mA[2] = {-1e30f, -1e30f}, lA[2] = {0.f, 0.f};
  float mB[2] = {-1e30f, -1e30f}, lB[2] = {0.f, 0.f};
  const f32x4 zero = {0.f, 0.f, 0.f, 0.f};

  auto process = [&](int kt, int qt, bf16x8 (&qf)[2][2], float (&m)[2],
                     float (&lsum)[2], f32x4 (&of)[2][4]) {
    // ---- S^T = K * Q^T : sf[mi][f][r] = S[q=mi*16+c][k=f*16+4g+r]
    f32x4 sf[2][8];
#pragma unroll
    for (int f = 0; f < 8; ++f) {
      const char* kr = (const char*)Kt + (f * 16 + c) * 128;
      bf16x8 kb0 = *(const bf16x8*)(kr + ((g * 16) ^ swz));
      bf16x8 kb1 = *(const bf16x8*)(kr + ((64 + g * 16) ^ swz));
#pragma unroll
      for (int mi = 0; mi < 2; ++mi) {
        f32x4 t = MFMA16(kb0, qf[mi][0], zero);
        sf[mi][f] = MFMA16(kb1, qf[mi][1], t);
      }
    }

    if (kt == qt) {  // causal mask on diagonal tile: k_local > q_local
#pragma unroll
      for (int mi = 0; mi < 2; ++mi) {
        const int qloc = w * 32 + mi * 16 + c;
#pragma unroll
        for (int f = 0; f < 8; ++f)
#pragma unroll
          for (int r = 0; r < 4; ++r)
            if (f * 16 + 4 * g + r > qloc) sf[mi][f][r] = -1e30f;
      }
    }

    // ---- online softmax (log2 domain), lane-local per q-row
    bf16x8 pa[2][4];
#pragma unroll
    for (int mi = 0; mi < 2; ++mi) {
      float pm = -1e30f;
#pragma unroll
      for (int f = 0; f < 8; ++f)
#pragma unroll
        for (int r = 0; r < 4; ++r) pm = fmaxf(pm, sf[mi][f][r]);
      pm = fmaxf(pm, __shfl_xor(pm, 16, 64));
      pm = fmaxf(pm, __shfl_xor(pm, 32, 64));
      const float mnew = fmaxf(m[mi], pm);
      const float sc = EXP2F(m[mi] - mnew);
      m[mi] = mnew;
      float rs = 0.f;
#pragma unroll
      for (int f = 0; f < 8; ++f)
#pragma unroll
        for (int r = 0; r < 4; ++r) {
          const float pv = EXP2F(sf[mi][f][r] - mnew);
          sf[mi][f][r] = pv;
          rs += pv;
        }
      rs += __shfl_xor(rs, 16, 64);
      rs += __shfl_xor(rs, 32, 64);
      lsum[mi] = lsum[mi] * sc + rs;
#pragma unroll
      for (int di = 0; di < 4; ++di) of[mi][di] *= sc;
      // pack P to bf16 A/B-frag slots: t covers k=32t..32t+31; slot s<4 -> f=2t,
      // s>=4 -> f=2t+1 (matches V^T b64-pair read order below)
#pragma unroll
      for (int t = 0; t < 4; ++t)
#pragma unroll
        for (int s = 0; s < 4; ++s) {
          pa[mi][t][s]     = (bf16)sf[mi][2 * t][s];
          pa[mi][t][4 + s] = (bf16)sf[mi][2 * t + 1][s];
        }
    }

    // ---- O^T += V^T * P^T (k-permutation identical on both operands)
#pragma unroll
    for (int di = 0; di < 4; ++di) {
      const char* vrow = (const char*)Vt + (di * 16 + c) * 256;
#pragma unroll
      for (int t = 0; t < 4; ++t) {
        bf16x4 v1 = *(const bf16x4*)(vrow + ((64 * t + 8 * g) ^ swz));
        bf16x4 v2 = *(const bf16x4*)(vrow + ((64 * t + 32 + 8 * g) ^ swz));
        bf16x8 va;
#pragma unroll
        for (int s = 0; s < 4; ++s) { va[s] = v1[s]; va[4 + s] = v2[s]; }
#pragma unroll
        for (int mi = 0; mi < 2; ++mi)
          of[mi][di] = MFMA16(va, pa[mi][t], of[mi][di]);
      }
    }
  };

  for (int kt = 0; kt <= qtB; ++kt) {
    // ---- stage K tile [128][64] (pre-swizzled source cols)
#pragma unroll
    for (int j = 0; j < 4; ++j) {
      const int row = w * 32 + j * 8 + (l >> 3);
      const int cs = ((l & 7) ^ (row & 7)) << 3;
      GLOAD_LDS16(qkv + (size_t)(b * SB + kt * 128 + row) * D3 + DD + h * 64 + cs,
                  (char*)Kt + w * 4096 + j * 1024);
    }
    // ---- stage V^T tile [64][128]
#pragma unroll
    for (int j = 0; j < 4; ++j) {
      const int row = w * 16 + j * 4 + (l >> 4);
      const int cs = ((l & 15) ^ (row & 7)) << 3;
      GLOAD_LDS16(vT + (size_t)(bh * 64 + row) * SB + kt * 128 + cs,
                  (char*)Vt + w * 4096 + j * 1024);
    }
    __syncthreads();

    if (kt <= qtA) process(kt, qtA, qfA, mA, lA, ofA);
    process(kt, qtB, qfB, mB, lB, ofB);
    __syncthreads();
  }

  // ---- normalize + store (8B packed stores, d = di*16+4g+r)
  auto store_tile = [&](int qt, float (&lsum)[2], f32x4 (&of)[2][4]) {
#pragma unroll
    for (int mi = 0; mi < 2; ++mi) {
      const float inv = 1.0f / lsum[mi];
      const size_t row = (size_t)(b * SB + qt * 128 + w * 32 + mi * 16 + c);
#pragma unroll
      for (int di = 0; di < 4; ++di) {
        bf16x4 st;
#pragma unroll
        for (int r = 0; r < 4; ++r) st[r] = (bf16)(of[mi][di][r] * inv);
        *(bf16x4*)(o + row * DD + h * 64 + di * 16 + 4 * g) = st;
      }
    }
  };
  store_tile(qtA, lA, ofA);
  store_tile(qtB, lB, ofB);
}

// ---------------------------------------------------------------------------
extern "C" void kernel_launch(void* const* d_in, const int* in_sizes, int n_in,
                              void* d_out, int out_size, void* d_ws, size_t ws_size,
                              hipStream_t stream) {
  const float* x  = (const float*)d_in[0];
  const float* w1 = (const float*)d_in[1];
  const float* b1 = (const float*)d_in[2];
  const float* w2 = (const float*)d_in[3];
  const float* b2 = (const float*)d_in[4];
  float* out = (float*)d_out;

  bf16* xb   = (bf16*)d_ws;
  bf16* w1b  = xb   + (size_t)8  * 1024 * 1024;
  bf16* w2b  = w1b  + (size_t)3  * 1024 * 1024;
  bf16* qkvb = w2b  + (size_t)1  * 1024 * 1024;
  bf16* vT   = qkvb + (size_t)8192 * 3072;
  bf16* ob   = vT   + (size_t)8  * 1024 * 1024;

  cast_bf16_kernel<<<2048, 256, 0, stream>>>(x,  xb,  (8 * 1024 * 1024) / 4);
  cast_bf16_kernel<<<768,  256, 0, stream>>>(w1, w1b, (3 * 1024 * 1024) / 4);
  cast_bf16_kernel<<<256,  256, 0, stream>>>(w2, w2b, (1 * 1024 * 1024) / 4);

  gemm_bt_kernel<1><<<dim3(24, 64), 256, 0, stream>>>(xb, w1b, b1, qkvb, 8192, 3072, 1024);
  vtrans_kernel<<<2048, 256, 0, stream>>>(qkvb, vT);
  attn_kernel<<<512, 256, 0, stream>>>(qkvb, vT, ob);
  gemm_bt_kernel<0><<<dim3(8, 64), 256, 0, stream>>>(ob, w2b, b2, out, 8192, 1024, 1024);
}

// Round 3
// 185.211 us; speedup vs baseline: 1.9871x; 1.0648x over previous
//
#include <hip/hip_runtime.h>
#include <stdint.h>

// ---------------------------------------------------------------------------
// MultiHeadAttention fwd: B=4 S=2048 D=1024 H=16 DH=64, fp32 in/out.
// Pipeline: cast->bf16 | QKV GEMM (MFMA, bias, q*=0.125*log2e) | V transpose |
//           flash attention (causal, paired q-tiles, dbuf prefetch staging,
//           in-register softmax + defer-max) | out GEMM (bias, fp32).
// ---------------------------------------------------------------------------

typedef __bf16 bf16;
typedef __attribute__((ext_vector_type(4))) __bf16 bf16x4;
typedef __attribute__((ext_vector_type(8))) __bf16 bf16x8;
typedef __attribute__((ext_vector_type(4))) float f32x4;

#define MFMA16(a, b, c) __builtin_amdgcn_mfma_f32_16x16x32_bf16((a), (b), (c), 0, 0, 0)

#if __has_builtin(__builtin_amdgcn_exp2f)
#define EXP2F(x) __builtin_amdgcn_exp2f(x)
#else
#define EXP2F(x) exp2f(x)
#endif

// async global->LDS, 16B per lane. LDS dest is wave-uniform base + lane*16.
#define GLOAD_LDS16(gp, lp)                                                    \
  __builtin_amdgcn_global_load_lds(                                            \
      (__attribute__((address_space(1))) void*)(gp),                           \
      (__attribute__((address_space(3))) void*)(lp), 16, 0, 0)

#define SB   2048              // sequence length
#define D3   3072              // 3*D
#define DD   1024              // D
#define QSCALE 0.18033688011112042f   // 1/sqrt(64) * log2(e): exp -> exp2

// ---------------------------------------------------------------------------
// fp32 -> bf16 cast, 4 elements/thread/iter
// ---------------------------------------------------------------------------
__global__ __launch_bounds__(256) void cast_bf16_kernel(
    const float* __restrict__ in, bf16* __restrict__ out, int n4) {
  int stride = gridDim.x * blockDim.x;
  for (int i = blockIdx.x * blockDim.x + threadIdx.x; i < n4; i += stride) {
    float4 v = ((const float4*)in)[i];
    bf16x4 p;
    p[0] = (bf16)v.x; p[1] = (bf16)v.y; p[2] = (bf16)v.z; p[3] = (bf16)v.w;
    *(bf16x4*)(out + (size_t)i * 4) = p;
  }
}

// ---------------------------------------------------------------------------
// NT GEMM: C[m,n] = sum_k A[m,k]*Bw[n,k] + bias[n]
// OUTMODE 1: bf16 out, q-part (n<1024) scaled by QSCALE. OUTMODE 0: fp32 out.
// 128x128 tile, BK=32, 256 thr (4 waves 2x2, each 64x64).
// ---------------------------------------------------------------------------
template <int OUTMODE>
__global__ __launch_bounds__(256) void gemm_bt_kernel(
    const bf16* __restrict__ A, const bf16* __restrict__ Bw,
    const float* __restrict__ bias, void* __restrict__ Cout,
    int M, int N, int K) {
  __shared__ __attribute__((aligned(16))) bf16 At[128 * 32];
  __shared__ __attribute__((aligned(16))) bf16 Bt[128 * 32];
  const int tid = threadIdx.x;
  const int w = tid >> 6, l = tid & 63;
  const int c = l & 15, g = l >> 4;
  const int wm = w >> 1, wn = w & 1;
  const int m0 = blockIdx.y * 128, n0 = blockIdx.x * 128;

  const int srow = w * 32 + (l >> 2);
  const int scol = (l & 3) * 8;
  const bf16* Ag = A + (size_t)(m0 + srow) * K + scol;
  const bf16* Bg = Bw + (size_t)(n0 + srow) * K + scol;
  char* AtB = (char*)At + w * 2048;
  char* BtB = (char*)Bt + w * 2048;

  f32x4 acc[4][4] = {};

  for (int k0 = 0; k0 < K; k0 += 32) {
    GLOAD_LDS16(Ag + k0,            AtB);
    GLOAD_LDS16(Ag + 16 * K + k0,   AtB + 1024);
    GLOAD_LDS16(Bg + k0,            BtB);
    GLOAD_LDS16(Bg + 16 * K + k0,   BtB + 1024);
    __syncthreads();

    bf16x8 aF[4], bF[4];
    const char* Ard = (const char*)At + (wm * 64 + c) * 64 + g * 16;
    const char* Brd = (const char*)Bt + (wn * 64 + c) * 64 + g * 16;
#pragma unroll
    for (int mi = 0; mi < 4; ++mi) aF[mi] = *(const bf16x8*)(Ard + mi * 1024);
#pragma unroll
    for (int ni = 0; ni < 4; ++ni) bF[ni] = *(const bf16x8*)(Brd + ni * 1024);
#pragma unroll
    for (int mi = 0; mi < 4; ++mi)
#pragma unroll
      for (int ni = 0; ni < 4; ++ni)
        acc[mi][ni] = MFMA16(aF[mi], bF[ni], acc[mi][ni]);
    __syncthreads();
  }

#pragma unroll
  for (int ni = 0; ni < 4; ++ni) {
    const int col = n0 + wn * 64 + ni * 16 + c;
    const float bv = bias[col];
#pragma unroll
    for (int mi = 0; mi < 4; ++mi) {
      const int row = m0 + wm * 64 + mi * 16 + 4 * g;
#pragma unroll
      for (int r = 0; r < 4; ++r) {
        float v = acc[mi][ni][r] + bv;
        if (OUTMODE == 1) {
          if (col < DD) v *= QSCALE;  // fold 1/sqrt(dh)*log2e into q
          ((bf16*)Cout)[(size_t)(row + r) * N + col] = (bf16)v;
        } else {
          ((float*)Cout)[(size_t)(row + r) * N + col] = v;
        }
      }
    }
  }
}

// ---------------------------------------------------------------------------
// V transpose: qkv v-part [b,s,h*64+d] -> vT[(bh*64+d)*2048 + s]
// ---------------------------------------------------------------------------
__global__ __launch_bounds__(256) void vtrans_kernel(
    const bf16* __restrict__ qkv, bf16* __restrict__ vT) {
  __shared__ __attribute__((aligned(16))) bf16 tt[64 * 72];
  const int tid = threadIdx.x;
  const int bh = blockIdx.x >> 5, st = blockIdx.x & 31;
  const int b = bh >> 4, h = bh & 15;
  const int s0 = st * 64;
  const int sr = tid >> 3, c0 = (tid & 7) * 8;
#pragma unroll
  for (int i = 0; i < 2; ++i) {
    const int srr = sr + i * 32;
    bf16x8 v = *(const bf16x8*)(qkv + (size_t)(b * SB + s0 + srr) * D3 + 2 * DD + h * 64 + c0);
    *(bf16x8*)(&tt[srr * 72 + c0]) = v;
  }
  __syncthreads();
  const int d = tid >> 2;
#pragma unroll
  for (int i = 0; i < 2; ++i) {
    const int sc = (tid & 3) * 2 + i;
    bf16x8 v;
#pragma unroll
    for (int j = 0; j < 8; ++j) v[j] = tt[(sc * 8 + j) * 72 + d];
    *(bf16x8*)(vT + (size_t)(bh * 64 + d) * SB + s0 + sc * 8) = v;
  }
}

// ---------------------------------------------------------------------------
// Causal flash attention, paired q-tiles, double-buffered prefetch staging.
// Grid 512: pair = bid>>6, bh = bid&63 (keeps one head's 8 blocks on 1 XCD).
// qtA = pair (light), qtB = 15-pair (heavy): every block = 17 tile-passes.
// Per pass: issue next K/V global_load_lds into buf^1, compute from buf,
// ONE __syncthreads (its implicit vmcnt(0) drains the overlapped prefetch).
// Swapped MFMA structure:
//   S^T = mfma(K, Q): lane holds P[q = mi*16+c][k = f*16+4g+r]  (in regs)
//   softmax: lane-local 32-max/sum + shfl_xor(16,32); defer-max THR=8 (log2)
//   O^T = mfma(V^T-frag, P-frag): of[mi][di][r] = O[q = mi*16+c][d = di*16+4g+r]
// ---------------------------------------------------------------------------
__global__ __launch_bounds__(256, 2) void attn_kernel(
    const bf16* __restrict__ qkv, const bf16* __restrict__ vT,
    bf16* __restrict__ o) {
  __shared__ __attribute__((aligned(16))) bf16 Kt[2][128 * 64];   // 2x16KB
  __shared__ __attribute__((aligned(16))) bf16 Vt[2][64 * 128];   // 2x16KB
  const int tid = threadIdx.x;
  const int w = tid >> 6, l = tid & 63;
  const int c = l & 15, g = l >> 4;
  const int pair = blockIdx.x >> 6, bh = blockIdx.x & 63;
  const int b = bh >> 4, h = bh & 15;
  const int qtA = pair, qtB = 15 - pair;
  const int swz = (c & 7) << 4;   // read-side XOR; staged rows pre-swizzled by (row&7)

  const bf16* qg = qkv + (size_t)(b * SB) * D3 + h * 64;

  // ---- stage K tile [128][64] + V^T tile [64][128] into buffer `buf`
  auto stage = [&](int kt, int buf) {
#pragma unroll
    for (int j = 0; j < 4; ++j) {
      const int row = w * 32 + j * 8 + (l >> 3);
      const int cs = ((l & 7) ^ (row & 7)) << 3;
      GLOAD_LDS16(qkv + (size_t)(b * SB + kt * 128 + row) * D3 + DD + h * 64 + cs,
                  (char*)&Kt[buf][0] + w * 4096 + j * 1024);
    }
#pragma unroll
    for (int j = 0; j < 4; ++j) {
      const int row = w * 16 + j * 4 + (l >> 4);
      const int cs = ((l & 15) ^ (row & 7)) << 3;
      GLOAD_LDS16(vT + (size_t)(bh * 64 + row) * SB + kt * 128 + cs,
                  (char*)&Vt[buf][0] + w * 4096 + j * 1024);
    }
  };

  stage(0, 0);

  // Q fragments for both tiles (B-operand layout: lane(c,g) = Q[q][d=dk*32+g*8..+7])
  bf16x8 qfA[2][2], qfB[2][2];
#pragma unroll
  for (int mi = 0; mi < 2; ++mi)
#pragma unroll
    for (int dk = 0; dk < 2; ++dk) {
      qfA[mi][dk] = *(const bf16x8*)(qg + (size_t)(qtA * 128 + w * 32 + mi * 16 + c) * D3 + dk * 32 + g * 8);
      qfB[mi][dk] = *(const bf16x8*)(qg + (size_t)(qtB * 128 + w * 32 + mi * 16 + c) * D3 + dk * 32 + g * 8);
    }

  f32x4 ofA[2][4] = {}, ofB[2][4] = {};
  float mA[2] = {-1e30f, -1e30f}, lA[2] = {0.f, 0.f};
  float mB[2] = {-1e30f, -1e30f}, lB[2] = {0.f, 0.f};
  const f32x4 zero = {0.f, 0.f, 0.f, 0.f};

  auto process = [&](int kt, int qt, int buf, bf16x8 (&qf)[2][2], float (&m)[2],
                     float (&lsum)[2], f32x4 (&of)[2][4]) {
    // ---- S^T = K * Q^T : sf[mi][f][r] = S[q=mi*16+c][k=f*16+4g+r]
    f32x4 sf[2][8];
#pragma unroll
    for (int f = 0; f < 8; ++f) {
      const char* kr = (const char*)&Kt[buf][0] + (f * 16 + c) * 128;
      bf16x8 kb0 = *(const bf16x8*)(kr + ((g * 16) ^ swz));
      bf16x8 kb1 = *(const bf16x8*)(kr + ((64 + g * 16) ^ swz));
#pragma unroll
      for (int mi = 0; mi < 2; ++mi) {
        f32x4 t = MFMA16(kb0, qf[mi][0], zero);
        sf[mi][f] = MFMA16(kb1, qf[mi][1], t);
      }
    }

    if (kt == qt) {  // causal mask on diagonal tile: k_local > q_local
#pragma unroll
      for (int mi = 0; mi < 2; ++mi) {
        const int qloc = w * 32 + mi * 16 + c;
#pragma unroll
        for (int f = 0; f < 8; ++f)
#pragma unroll
          for (int r = 0; r < 4; ++r)
            if (f * 16 + 4 * g + r > qloc) sf[mi][f][r] = -1e30f;
      }
    }

    // ---- online softmax (log2 domain), lane-local per q-row, defer-max THR=8
    bf16x8 pa[2][4];
#pragma unroll
    for (int mi = 0; mi < 2; ++mi) {
      float pm = -1e30f;
#pragma unroll
      for (int f = 0; f < 8; ++f)
#pragma unroll
        for (int r = 0; r < 4; ++r) pm = fmaxf(pm, sf[mi][f][r]);
      pm = fmaxf(pm, __shfl_xor(pm, 16, 64));
      pm = fmaxf(pm, __shfl_xor(pm, 32, 64));
      if (__any(pm > m[mi] + 8.f)) {   // rescale only when max grew materially
        const float mnew = fmaxf(m[mi], pm);
        const float sc = EXP2F(m[mi] - mnew);
        m[mi] = mnew;
        lsum[mi] *= sc;
#pragma unroll
        for (int di = 0; di < 4; ++di) of[mi][di] *= sc;
      }
      float rs = 0.f;
#pragma unroll
      for (int f = 0; f < 8; ++f)
#pragma unroll
        for (int r = 0; r < 4; ++r) {
          const float pv = EXP2F(sf[mi][f][r] - m[mi]);
          sf[mi][f][r] = pv;
          rs += pv;
        }
      rs += __shfl_xor(rs, 16, 64);
      rs += __shfl_xor(rs, 32, 64);
      lsum[mi] += rs;
      // pack P to bf16 frag slots: t covers k=32t..32t+31; s<4 -> f=2t,
      // s>=4 -> f=2t+1 (matches V^T b64-pair read order below)
#pragma unroll
      for (int t = 0; t < 4; ++t)
#pragma unroll
        for (int s = 0; s < 4; ++s) {
          pa[mi][t][s]     = (bf16)sf[mi][2 * t][s];
          pa[mi][t][4 + s] = (bf16)sf[mi][2 * t + 1][s];
        }
    }

    // ---- O^T += V^T * P^T (k-permutation identical on both operands)
#pragma unroll
    for (int di = 0; di < 4; ++di) {
      const char* vrow = (const char*)&Vt[buf][0] + (di * 16 + c) * 256;
#pragma unroll
      for (int t = 0; t < 4; ++t) {
        bf16x4 v1 = *(const bf16x4*)(vrow + ((64 * t + 8 * g) ^ swz));
        bf16x4 v2 = *(const bf16x4*)(vrow + ((64 * t + 32 + 8 * g) ^ swz));
        bf16x8 va;
#pragma unroll
        for (int s = 0; s < 4; ++s) { va[s] = v1[s]; va[4 + s] = v2[s]; }
#pragma unroll
        for (int mi = 0; mi < 2; ++mi)
          of[mi][di] = MFMA16(va, pa[mi][t], of[mi][di]);
      }
    }
  };

  __syncthreads();  // stage(0) complete (implicit vmcnt(0) drain + barrier)

  int buf = 0;
  for (int kt = 0; kt <= qtB; ++kt) {
    if (kt < qtB) stage(kt + 1, buf ^ 1);   // prefetch overlaps compute below
    if (kt <= qtA) process(kt, qtA, buf, qfA, mA, lA, ofA);
    process(kt, qtB, buf, qfB, mB, lB, ofB);
    __syncthreads();  // drains prefetch (cheap now) + protects buf swap
    buf ^= 1;
  }

  // ---- normalize + store (8B packed stores, d = di*16+4g+r)
  auto store_tile = [&](int qt, float (&lsum)[2], f32x4 (&of)[2][4]) {
#pragma unroll
    for (int mi = 0; mi < 2; ++mi) {
      const float inv = 1.0f / lsum[mi];
      const size_t row = (size_t)(b * SB + qt * 128 + w * 32 + mi * 16 + c);
#pragma unroll
      for (int di = 0; di < 4; ++di) {
        bf16x4 st;
#pragma unroll
        for (int r = 0; r < 4; ++r) st[r] = (bf16)(of[mi][di][r] * inv);
        *(bf16x4*)(o + row * DD + h * 64 + di * 16 + 4 * g) = st;
      }
    }
  };
  store_tile(qtA, lA, ofA);
  store_tile(qtB, lB, ofB);
}

// ---------------------------------------------------------------------------
extern "C" void kernel_launch(void* const* d_in, const int* in_sizes, int n_in,
                              void* d_out, int out_size, void* d_ws, size_t ws_size,
                              hipStream_t stream) {
  const float* x  = (const float*)d_in[0];
  const float* w1 = (const float*)d_in[1];
  const float* b1 = (const float*)d_in[2];
  const float* w2 = (const float*)d_in[3];
  const float* b2 = (const float*)d_in[4];
  float* out = (float*)d_out;

  bf16* xb   = (bf16*)d_ws;
  bf16* w1b  = xb   + (size_t)8  * 1024 * 1024;
  bf16* w2b  = w1b  + (size_t)3  * 1024 * 1024;
  bf16* qkvb = w2b  + (size_t)1  * 1024 * 1024;
  bf16* vT   = qkvb + (size_t)8192 * 3072;
  bf16* ob   = vT   + (size_t)8  * 1024 * 1024;

  cast_bf16_kernel<<<2048, 256, 0, stream>>>(x,  xb,  (8 * 1024 * 1024) / 4);
  cast_bf16_kernel<<<768,  256, 0, stream>>>(w1, w1b, (3 * 1024 * 1024) / 4);
  cast_bf16_kernel<<<256,  256, 0, stream>>>(w2, w2b, (1 * 1024 * 1024) / 4);

  gemm_bt_kernel<1><<<dim3(24, 64), 256, 0, stream>>>(xb, w1b, b1, qkvb, 8192, 3072, 1024);
  vtrans_kernel<<<2048, 256, 0, stream>>>(qkvb, vT);
  attn_kernel<<<512, 256, 0, stream>>>(qkvb, vT, ob);
  gemm_bt_kernel<0><<<dim3(8, 64), 256, 0, stream>>>(ob, w2b, b2, out, 8192, 1024, 1024);
}